// Round 1
// baseline (491.442 us; speedup 1.0000x reference)
//
#include <hip/hip_runtime.h>

#define NSEG 16384
#define EPS 1e-12f

// Phase 1: per-segment partial sums of p*p, t*t, p*t.
// batch_map is sorted, so "first seg == last seg" implies all equal.
__global__ void seg_partial_kernel(const float4* __restrict__ p,
                                   const float4* __restrict__ t,
                                   const int4* __restrict__ s,
                                   float* __restrict__ pp,
                                   float* __restrict__ tt,
                                   float* __restrict__ pd,
                                   int nvec) {
    const int lane = threadIdx.x & 63;
    int idx = blockIdx.x * blockDim.x + threadIdx.x;
    const int stride = gridDim.x * blockDim.x;

    for (int i = idx; i < nvec; i += stride) {
        float4 pv = p[i];
        float4 tv = t[i];
        int4  sv = s[i];

        // wave spans 64*4 = 256 contiguous elements; sorted map =>
        // uniform iff first lane's first seg == last lane's last seg
        int s_first = __shfl(sv.x, 0);
        int s_last  = __shfl(sv.w, 63);

        if (s_first == s_last) {
            // fast path: whole wave in one segment
            float a = pv.x * pv.x + pv.y * pv.y + pv.z * pv.z + pv.w * pv.w;
            float b = tv.x * tv.x + tv.y * tv.y + tv.z * tv.z + tv.w * tv.w;
            float c = pv.x * tv.x + pv.y * tv.y + pv.z * tv.z + pv.w * tv.w;
            #pragma unroll
            for (int off = 32; off > 0; off >>= 1) {
                a += __shfl_down(a, off);
                b += __shfl_down(b, off);
                c += __shfl_down(c, off);
            }
            if (lane == 0) {
                atomicAdd(&pp[s_first], a);
                atomicAdd(&tt[s_first], b);
                atomicAdd(&pd[s_first], c);
            }
        } else {
            // boundary wave (~B of these total). Per-lane handling.
            if (sv.x == sv.w) {
                // lane's 4 elements all in one segment
                float a = pv.x * pv.x + pv.y * pv.y + pv.z * pv.z + pv.w * pv.w;
                float b = tv.x * tv.x + tv.y * tv.y + tv.z * tv.z + tv.w * tv.w;
                float c = pv.x * tv.x + pv.y * tv.y + pv.z * tv.z + pv.w * tv.w;
                atomicAdd(&pp[sv.x], a);
                atomicAdd(&tt[sv.x], b);
                atomicAdd(&pd[sv.x], c);
            } else {
                // segment boundary inside the lane's 4 elements
                atomicAdd(&pp[sv.x], pv.x * pv.x);
                atomicAdd(&tt[sv.x], tv.x * tv.x);
                atomicAdd(&pd[sv.x], pv.x * tv.x);
                atomicAdd(&pp[sv.y], pv.y * pv.y);
                atomicAdd(&tt[sv.y], tv.y * tv.y);
                atomicAdd(&pd[sv.y], pv.y * tv.y);
                atomicAdd(&pp[sv.z], pv.z * pv.z);
                atomicAdd(&tt[sv.z], tv.z * tv.z);
                atomicAdd(&pd[sv.z], pv.z * tv.z);
                atomicAdd(&pp[sv.w], pv.w * pv.w);
                atomicAdd(&tt[sv.w], tv.w * tv.w);
                atomicAdd(&pd[sv.w], pv.w * tv.w);
            }
        }
    }
}

// Phase 2: cosine per segment, mean(1 - cos) -> scalar.
__global__ void finalize_kernel(const float* __restrict__ pp,
                                const float* __restrict__ tt,
                                const float* __restrict__ pd,
                                float* __restrict__ out) {
    float local = 0.0f;
    for (int i = threadIdx.x; i < NSEG; i += blockDim.x) {
        float denom = sqrtf(pp[i]) * sqrtf(tt[i]);
        float c = pd[i] / fmaxf(denom, EPS);
        local += 1.0f - c;
    }
    #pragma unroll
    for (int off = 32; off > 0; off >>= 1)
        local += __shfl_down(local, off);

    __shared__ float wsum[16];
    int wid = threadIdx.x >> 6;
    if ((threadIdx.x & 63) == 0) wsum[wid] = local;
    __syncthreads();
    if (threadIdx.x == 0) {
        float tot = 0.0f;
        int nw = blockDim.x >> 6;
        for (int w = 0; w < nw; ++w) tot += wsum[w];
        out[0] = tot / (float)NSEG;
    }
}

extern "C" void kernel_launch(void* const* d_in, const int* in_sizes, int n_in,
                              void* d_out, int out_size, void* d_ws, size_t ws_size,
                              hipStream_t stream) {
    const float4* p = (const float4*)d_in[0];
    const float4* t = (const float4*)d_in[1];
    const int4*   s = (const int4*)d_in[2];
    int n = in_sizes[0];
    int nvec = n / 4;

    float* pp = (float*)d_ws;
    float* tt = pp + NSEG;
    float* pd = tt + NSEG;

    // zero the accumulators (harness does not re-poison ws between replays)
    hipMemsetAsync(d_ws, 0, 3 * NSEG * sizeof(float), stream);

    int threads = 256;
    int blocks = 2048;  // ~8 float4 iters/thread; grid-stride handles remainder
    seg_partial_kernel<<<blocks, threads, 0, stream>>>(p, t, s, pp, tt, pd, nvec);
    finalize_kernel<<<1, 1024, 0, stream>>>(pp, tt, pd, (float*)d_out);
}

// Round 2
// 41.003 us; speedup vs baseline: 11.9856x; 11.9856x over previous
//
#include <hip/hip_runtime.h>

#define NSEG 16384
#define EPS 1e-12f

// Kernel 1: start[b] = lower_bound(batch_map, b) for b in [0, NSEG].
// batch_map is sorted; values in [0, NSEG). start[NSEG] = n.
__global__ void bsearch_kernel(const int* __restrict__ map,
                               int* __restrict__ start, int n) {
    int b = blockIdx.x * blockDim.x + threadIdx.x;
    if (b > NSEG) return;
    int lo = 0, hi = n;
    while (lo < hi) {
        int mid = (lo + hi) >> 1;
        if (map[mid] < b) lo = mid + 1; else hi = mid;
    }
    start[b] = lo;
}

// Kernel 2: one wave per segment. Reduce sum(p*p), sum(t*t), sum(p*t)
// over [start[seg], start[seg+1]) and write loss[seg] = 1 - cosine.
// No atomics anywhere.
__global__ void seg_cos_kernel(const float* __restrict__ p,
                               const float* __restrict__ t,
                               const int* __restrict__ start,
                               float* __restrict__ loss) {
    const int wid  = threadIdx.x >> 6;
    const int lane = threadIdx.x & 63;
    const int seg  = blockIdx.x * (blockDim.x >> 6) + wid;
    if (seg >= NSEG) return;

    const int s0 = start[seg];
    const int s1 = start[seg + 1];

    float a = 0.0f, b = 0.0f, c = 0.0f;

    const int a0 = (s0 + 3) & ~3;  // first 16B-aligned element
    const int a1 = s1 & ~3;        // end of aligned body

    if (a1 <= a0) {
        // tiny segment: all scalar
        for (int i = s0 + lane; i < s1; i += 64) {
            float pv = p[i], tv = t[i];
            a += pv * pv; b += tv * tv; c += pv * tv;
        }
    } else {
        // scalar head [s0, a0): < 4 elements
        int i = s0 + lane;
        if (i < a0) {
            float pv = p[i], tv = t[i];
            a += pv * pv; b += tv * tv; c += pv * tv;
        }
        // scalar tail [a1, s1): < 4 elements
        i = a1 + lane;
        if (i < s1) {
            float pv = p[i], tv = t[i];
            a += pv * pv; b += tv * tv; c += pv * tv;
        }
        // vectorized body [a0, a1), float4-aligned
        const float4* p4 = (const float4*)p;
        const float4* t4 = (const float4*)t;
        const int v0 = a0 >> 2, v1 = a1 >> 2;
        for (int v = v0 + lane; v < v1; v += 64) {
            float4 pv = p4[v], tv = t4[v];
            a += pv.x * pv.x + pv.y * pv.y + pv.z * pv.z + pv.w * pv.w;
            b += tv.x * tv.x + tv.y * tv.y + tv.z * tv.z + tv.w * tv.w;
            c += pv.x * tv.x + pv.y * tv.y + pv.z * tv.z + pv.w * tv.w;
        }
    }

    #pragma unroll
    for (int off = 32; off > 0; off >>= 1) {
        a += __shfl_down(a, off);
        b += __shfl_down(b, off);
        c += __shfl_down(c, off);
    }

    if (lane == 0) {
        float denom = sqrtf(a) * sqrtf(b);
        float cosv = c / fmaxf(denom, EPS);
        loss[seg] = 1.0f - cosv;
    }
}

// Kernel 3: out = mean(loss)
__global__ void finalize_kernel(const float* __restrict__ loss,
                                float* __restrict__ out) {
    float local = 0.0f;
    for (int i = threadIdx.x; i < NSEG; i += blockDim.x)
        local += loss[i];
    #pragma unroll
    for (int off = 32; off > 0; off >>= 1)
        local += __shfl_down(local, off);

    __shared__ float wsum[16];
    int wid = threadIdx.x >> 6;
    if ((threadIdx.x & 63) == 0) wsum[wid] = local;
    __syncthreads();
    if (threadIdx.x == 0) {
        float tot = 0.0f;
        int nw = blockDim.x >> 6;
        for (int w = 0; w < nw; ++w) tot += wsum[w];
        out[0] = tot / (float)NSEG;
    }
}

extern "C" void kernel_launch(void* const* d_in, const int* in_sizes, int n_in,
                              void* d_out, int out_size, void* d_ws, size_t ws_size,
                              hipStream_t stream) {
    const float* p = (const float*)d_in[0];
    const float* t = (const float*)d_in[1];
    const int*   s = (const int*)d_in[2];
    int n = in_sizes[0];

    int*   start = (int*)d_ws;                 // NSEG+1 ints
    float* loss  = (float*)(start + NSEG + 2); // NSEG floats (keep 8B align)

    // 1) segment boundaries via binary search (writes all of start[])
    bsearch_kernel<<<(NSEG + 1 + 255) / 256, 256, 0, stream>>>(s, start, n);

    // 2) one wave per segment, 4 waves per block
    seg_cos_kernel<<<NSEG / 4, 256, 0, stream>>>(p, t, start, loss);

    // 3) mean
    finalize_kernel<<<1, 1024, 0, stream>>>(loss, (float*)d_out);
}